// Round 1
// baseline (883.064 us; speedup 1.0000x reference)
//
#include <hip/hip_runtime.h>
#include <math.h>

#define NVOCAB 50000
#define NE 256
#define NS 512
#define NB 4
#define NT 2048

// workspace float offsets
#define OFF_G     0
#define OFF_GMAT  256
#define OFF_CW1   (OFF_GMAT + 65536)
#define OFF_DW1   (OFF_CW1 + 65536)
#define OFF_XS    (OFF_DW1 + 131072)
#define OFF_H2    (OFF_XS + 524288)
#define OFF_CA    (OFF_H2 + 524288)
// bf16 split buffers (ushorts packed into float ws):
#define OFF_AH    (OFF_CA + 128)        // h2 hi: 2048*256 ushort = 262144 floats
#define OFF_AL    (OFF_AH + 262144)     // h2 lo
#define OFF_BH    (OFF_AL + 262144)     // dw3^T hi: 50000*256 ushort = 6400000 floats
#define OFF_BL    (OFF_BH + 6400000)    // dw3^T lo
#define WS_TOTAL_F (OFF_BL + 6400000)   // ~58.5 MB

typedef short bf16x8 __attribute__((ext_vector_type(8)));
typedef float f32x4 __attribute__((ext_vector_type(4)));
typedef unsigned short us8 __attribute__((ext_vector_type(8)));

__device__ __forceinline__ float gelu_exact(float x) {
  return 0.5f * x * (1.0f + erff(x * 0.70710678118654752440f));
}

__device__ __forceinline__ unsigned short f2bf(float x) {
  unsigned u = __float_as_uint(x);
  u += 0x7FFFu + ((u >> 16) & 1u);   // round-to-nearest-even
  return (unsigned short)(u >> 16);
}
__device__ __forceinline__ float bf2f(unsigned short h) {
  return __uint_as_float(((unsigned)h) << 16);
}

// --- prep1: spectral kernel g[256] + zero concept accumulator ---
__global__ __launch_bounds__(256) void k_prep1(float* ws) {
  int t = threadIdx.x;
  if (blockIdx.x == 0) {
    float sum = 0.f;
    for (int m = 0; m < 256; m++) {
      int mm = (m <= 128) ? m : (256 - m);
      float c = cosf(1.5f * atanf(logf(4.0f * (float)mm + 1e-6f)));
      int r = (m * t) & 255;
      sum += c * cosf((float)r * (6.283185307179586f / 256.0f));
    }
    ws[OFF_G + t] = sum * (1.0f / 256.0f);
  } else {
    if (t < 128) ws[OFF_CA + t] = 0.0f;
  }
}

// --- prep2: Gmat[d][t] = g[(t-d)&255]; effective (block-summed) cw1/dw1 ---
__global__ __launch_bounds__(256) void k_prep2(const float* cw1, const float* dw1, float* ws) {
  int b = blockIdx.x, t = threadIdx.x;
  if (b < 256) {
    int d = b;
    ws[OFF_GMAT + d * 256 + t] = ws[OFF_G + ((t - d) & 255)];
  } else if (b < 512) {
    int r = b - 256;
    float s = 0.f;
    #pragma unroll
    for (int q = 0; q < 4; q++) s += cw1[(q * 256 + r) * 256 + t];
    ws[OFF_CW1 + r * 256 + t] = s;
  } else {
    int idx = (b - 512) * 256 + t;
    int r = idx >> 9, c = idx & 511;
    float s = 0.f;
    #pragma unroll
    for (int q = 0; q < 4; q++) s += dw1[(q * 256 + r) * 512 + c];
    ws[OFF_DW1 + idx] = s;
  }
}

// --- spectral: xs[i][t] = (sum_d |x[i][d]| * Gmat[d][t]) * sign(x[i][t]) ---
__global__ __launch_bounds__(256) void k_spectral(const int* ids, const float* emb, float* ws) {
  __shared__ __align__(16) float xb[8][256];
  int t = threadIdx.x;
  int i0 = blockIdx.x * 8;
  #pragma unroll
  for (int rr = 0; rr < 8; rr++) {
    int id = ids[i0 + rr];
    xb[rr][t] = emb[id * 256 + t];
  }
  __syncthreads();
  float acc[8] = {0, 0, 0, 0, 0, 0, 0, 0};
  const float* Gm = ws + OFF_GMAT;
  for (int d = 0; d < 256; d += 4) {
    float w0 = Gm[(d + 0) * 256 + t];
    float w1 = Gm[(d + 1) * 256 + t];
    float w2 = Gm[(d + 2) * 256 + t];
    float w3 = Gm[(d + 3) * 256 + t];
    #pragma unroll
    for (int rr = 0; rr < 8; rr++) {
      float4 a4 = *(const float4*)&xb[rr][d];
      acc[rr] += fabsf(a4.x) * w0 + fabsf(a4.y) * w1 + fabsf(a4.z) * w2 + fabsf(a4.w) * w3;
    }
  }
  #pragma unroll
  for (int rr = 0; rr < 8; rr++) {
    float x = xb[rr][t];
    float sg = (x > 0.f) ? 1.f : ((x < 0.f) ? -1.f : 0.f);
    ws[OFF_XS + (i0 + rr) * 256 + t] = acc[rr] * sg;
  }
}

// --- concept recognizer + per-block partial mean into accumulator ---
__global__ __launch_bounds__(256) void k_concept(const float* cb1, const float* cw2, const float* cb2,
                                                 const float* cw3, const float* cb3, float* ws) {
  __shared__ __align__(16) float xs_s[8][256];
  __shared__ __align__(16) float c1s[8][256];
  __shared__ float c2s[8][64];
  __shared__ float c3s[8][32];
  int t = threadIdx.x;
  int i0 = blockIdx.x * 8;
  #pragma unroll
  for (int rr = 0; rr < 8; rr++) xs_s[rr][t] = ws[OFF_XS + (i0 + rr) * 256 + t];
  __syncthreads();
  const float* cw1eff = ws + OFF_CW1;
  float acc[8] = {0, 0, 0, 0, 0, 0, 0, 0};
  for (int d = 0; d < 256; d += 4) {
    float w0 = cw1eff[(d + 0) * 256 + t];
    float w1 = cw1eff[(d + 1) * 256 + t];
    float w2 = cw1eff[(d + 2) * 256 + t];
    float w3 = cw1eff[(d + 3) * 256 + t];
    #pragma unroll
    for (int rr = 0; rr < 8; rr++) {
      float4 a4 = *(const float4*)&xs_s[rr][d];
      acc[rr] += a4.x * w0 + a4.y * w1 + a4.z * w2 + a4.w * w3;
    }
  }
  float b1v = cb1[t];
  #pragma unroll
  for (int rr = 0; rr < 8; rr++) c1s[rr][t] = fmaxf(acc[rr] + b1v, 0.f);
  __syncthreads();
  {
    int e = t & 63, grp = t >> 6;
    float a0 = 0.f, a1 = 0.f;
    for (int d = 0; d < 256; d++) {
      float w = cw2[d * 64 + e];
      a0 += c1s[grp * 2 + 0][d] * w;
      a1 += c1s[grp * 2 + 1][d] * w;
    }
    float b2v = cb2[e];
    c2s[grp * 2 + 0][e] = fmaxf(a0 + b2v, 0.f);
    c2s[grp * 2 + 1][e] = fmaxf(a1 + b2v, 0.f);
  }
  __syncthreads();
  {
    int v = t & 31, grp = t >> 5;
    float a = 0.f;
    for (int d = 0; d < 64; d++) a += c2s[grp][d] * cw3[d * 32 + v];
    c3s[grp][v] = a + cb3[v];
  }
  __syncthreads();
  if (t < 32) {
    float s = 0.f;
    #pragma unroll
    for (int rr = 0; rr < 8; rr++) s += c3s[rr][t];
    int bb = i0 >> 9;
    atomicAdd(ws + OFF_CA + bb * 32 + t, s * (1.0f / 512.0f));
  }
}

// --- structure generator (tiny) + emit concept_vector ---
__global__ __launch_bounds__(128) void k_structure(const float* sw1, const float* sb1,
                                                   const float* sw2, const float* sb2,
                                                   float* out, const float* ws) {
  __shared__ float cv[4][32];
  __shared__ float s1[4][16];
  int t = threadIdx.x;
  {
    int b = t >> 5, j = t & 31;
    float v = ws[OFF_CA + t];
    cv[b][j] = v;
    out[102400000 + t] = v;
  }
  __syncthreads();
  if (t < 64) {
    int b = t >> 4, e = t & 15;
    float a = sb1[e];
    for (int d = 0; d < 32; d++) a += cv[b][d] * sw1[d * 16 + e];
    s1[b][e] = fmaxf(a, 0.f);
  }
  __syncthreads();
  if (t < 32) {
    int b = t >> 3, e = t & 7;
    float a = sb2[e];
    for (int d = 0; d < 16; d++) a += s1[b][d] * sw2[d * 8 + e];
    out[102400128 + t] = 1.0f / (1.0f + expf(-a));
  }
}

// --- decoder mid: h1 = gelu(xs@DW1eff+db1); LN; h2 = gelu(h1@dw2+db2) ---
__global__ __launch_bounds__(256) void k_decoder(const float* db1, const float* lng, const float* lnb,
                                                 const float* dw2, const float* db2, float* ws) {
  __shared__ __align__(16) float xs_s[8][256];
  __shared__ __align__(16) float h1s[8][512];
  __shared__ float mu_s[8], rs_s[8];
  int t = threadIdx.x;
  int i0 = blockIdx.x * 8;
  #pragma unroll
  for (int rr = 0; rr < 8; rr++) xs_s[rr][t] = ws[OFF_XS + (i0 + rr) * 256 + t];
  __syncthreads();
  const float* dw1eff = ws + OFF_DW1;
  float a1[8] = {0, 0, 0, 0, 0, 0, 0, 0};
  float a2[8] = {0, 0, 0, 0, 0, 0, 0, 0};
  for (int d = 0; d < 256; d += 2) {
    float wa0 = dw1eff[(d + 0) * 512 + t];
    float wb0 = dw1eff[(d + 0) * 512 + t + 256];
    float wa1 = dw1eff[(d + 1) * 512 + t];
    float wb1 = dw1eff[(d + 1) * 512 + t + 256];
    #pragma unroll
    for (int rr = 0; rr < 8; rr++) {
      float2 x2 = *(const float2*)&xs_s[rr][d];
      a1[rr] += x2.x * wa0 + x2.y * wa1;
      a2[rr] += x2.x * wb0 + x2.y * wb1;
    }
  }
  float ba = db1[t], bb = db1[t + 256];
  #pragma unroll
  for (int rr = 0; rr < 8; rr++) {
    h1s[rr][t]       = gelu_exact(a1[rr] + ba);
    h1s[rr][t + 256] = gelu_exact(a2[rr] + bb);
  }
  __syncthreads();
  {
    int rr = t >> 5, q = t & 31;
    float sum = 0.f, sq = 0.f;
    for (int j = q; j < 512; j += 32) {
      float v = h1s[rr][j];
      sum += v; sq += v * v;
    }
    #pragma unroll
    for (int off = 16; off >= 1; off >>= 1) {
      sum += __shfl_down(sum, off, 32);
      sq  += __shfl_down(sq, off, 32);
    }
    if (q == 0) {
      float mu = sum * (1.0f / 512.0f);
      float var = sq * (1.0f / 512.0f) - mu * mu;
      mu_s[rr] = mu;
      rs_s[rr] = rsqrtf(var + 1e-5f);
    }
  }
  __syncthreads();
  {
    float ga = lng[t], bba = lnb[t], gb = lng[t + 256], bbb = lnb[t + 256];
    #pragma unroll
    for (int rr = 0; rr < 8; rr++) {
      float m = mu_s[rr], r = rs_s[rr];
      h1s[rr][t]       = (h1s[rr][t]       - m) * r * ga + bba;
      h1s[rr][t + 256] = (h1s[rr][t + 256] - m) * r * gb + bbb;
    }
  }
  __syncthreads();
  float acc[8] = {0, 0, 0, 0, 0, 0, 0, 0};
  for (int d = 0; d < 512; d += 2) {
    float w0 = dw2[(d + 0) * 256 + t];
    float w1 = dw2[(d + 1) * 256 + t];
    #pragma unroll
    for (int rr = 0; rr < 8; rr++) {
      float2 h2v = *(const float2*)&h1s[rr][d];
      acc[rr] += h2v.x * w0 + h2v.y * w1;
    }
  }
  float b2v = db2[t];
  #pragma unroll
  for (int rr = 0; rr < 8; rr++)
    ws[OFF_H2 + (i0 + rr) * 256 + t] = gelu_exact(acc[rr] + b2v);
}

// --- splitA: h2 fp32 [2048][256] -> Ah, Al bf16 ---
__global__ __launch_bounds__(256) void k_splitA(float* ws) {
  int idx = (blockIdx.x * 256 + threadIdx.x) * 8;   // grid 256 -> covers 524288
  const float* h2 = ws + OFF_H2;
  unsigned short* Ah = (unsigned short*)(ws + OFF_AH);
  unsigned short* Al = (unsigned short*)(ws + OFF_AL);
  float4 v0 = *(const float4*)&h2[idx];
  float4 v1 = *(const float4*)&h2[idx + 4];
  float v[8] = {v0.x, v0.y, v0.z, v0.w, v1.x, v1.y, v1.z, v1.w};
  us8 h, l;
  #pragma unroll
  for (int i = 0; i < 8; i++) {
    unsigned short hb = f2bf(v[i]);
    h[i] = (short)hb;
    l[i] = (short)f2bf(v[i] - bf2f(hb));
  }
  *(us8*)&Ah[idx] = h;
  *(us8*)&Al[idx] = l;
}

// --- splitB: dw3 fp32 [256][50000] -> Bh, Bl bf16 transposed [50000][256] ---
__global__ __launch_bounds__(256) void k_splitB(const float* dw3, float* ws) {
  __shared__ float tile[64][65];
  int t = threadIdx.x;
  int n0 = blockIdx.x * 64;       // 782 blocks, tail block has 16 valid cols
  int k0 = blockIdx.y * 64;       // 4 blocks
  int tc = t & 15, tr = t >> 4;
  #pragma unroll
  for (int p = 0; p < 4; p++) {
    int k = k0 + tr + p * 16;
    int n = n0 + tc * 4;
    float4 v = make_float4(0.f, 0.f, 0.f, 0.f);
    if (n < NVOCAB) v = *(const float4*)&dw3[(size_t)k * NVOCAB + n];  // 50000%4==0
    tile[tr + p * 16][tc * 4 + 0] = v.x;
    tile[tr + p * 16][tc * 4 + 1] = v.y;
    tile[tr + p * 16][tc * 4 + 2] = v.z;
    tile[tr + p * 16][tc * 4 + 3] = v.w;
  }
  __syncthreads();
  int nl = t >> 2, kq = (t & 3) * 16;
  int n = n0 + nl;
  if (n < NVOCAB) {
    unsigned short* Bh = (unsigned short*)(ws + OFF_BH);
    unsigned short* Bl = (unsigned short*)(ws + OFF_BL);
    us8 h0, h1, l0, l1;
    #pragma unroll
    for (int i = 0; i < 8; i++) {
      float x = tile[kq + i][nl];
      unsigned short hb = f2bf(x);
      h0[i] = (short)hb;
      l0[i] = (short)f2bf(x - bf2f(hb));
    }
    #pragma unroll
    for (int i = 0; i < 8; i++) {
      float x = tile[kq + 8 + i][nl];
      unsigned short hb = f2bf(x);
      h1[i] = (short)hb;
      l1[i] = (short)f2bf(x - bf2f(hb));
    }
    size_t base = (size_t)n * 256 + k0 + kq;
    *(us8*)&Bh[base] = h0;
    *(us8*)&Bh[base + 8] = h1;
    *(us8*)&Bl[base] = l0;
    *(us8*)&Bl[base + 8] = l1;
  }
}

// --- logits via MFMA: C = (Ah+Al)(Bh+Bl) ~ AhBh + AhBl + AlBh, fp32 accum ---
// 128x128 tile, BK=32, 4 waves (2x2), 4x4 frags of 16x16x32 per wave.
// LDS row per m (or n): 8 slots of 16B (slots 0-3 hi k-octs, 4-7 lo), XOR-swizzled.
__global__ __launch_bounds__(256, 2) void k_logits_mfma(const float* db3, float* out, const float* ws) {
  __shared__ __align__(16) unsigned short As[128 * 64];
  __shared__ __align__(16) unsigned short Bs[128 * 64];
  const unsigned short* Ah = (const unsigned short*)(ws + OFF_AH);
  const unsigned short* Al = (const unsigned short*)(ws + OFF_AL);
  const unsigned short* Bh = (const unsigned short*)(ws + OFF_BH);
  const unsigned short* Bl = (const unsigned short*)(ws + OFF_BL);
  int t = threadIdx.x;
  int n0 = blockIdx.x * 128;
  int m0 = blockIdx.y * 128;
  int lane = t & 63;
  int w = t >> 6;
  int wm = w >> 1, wn = w & 1;
  int rr = lane & 15, g = lane >> 4;

  f32x4 acc[4][4];
  #pragma unroll
  for (int i = 0; i < 4; i++)
    #pragma unroll
    for (int j = 0; j < 4; j++)
      acc[i][j] = (f32x4){0.f, 0.f, 0.f, 0.f};

  const us8 zero8 = {0, 0, 0, 0, 0, 0, 0, 0};

  for (int kk = 0; kk < 8; kk++) {
    int k0 = kk * 32;
    us8 ga[4], gb[4];
    #pragma unroll
    for (int p = 0; p < 4; p++) {
      int q = t + p * 256;            // 0..1023
      int row = q >> 3, slot = q & 7; // row 0..127, slot 0..7
      int joct = slot & 3;
      const unsigned short* srcA = (slot < 4) ? Ah : Al;
      ga[p] = *(const us8*)&srcA[(size_t)(m0 + row) * 256 + k0 + joct * 8];
      int n = n0 + row;
      if (n < NVOCAB) {
        const unsigned short* srcB = (slot < 4) ? Bh : Bl;
        gb[p] = *(const us8*)&srcB[(size_t)n * 256 + k0 + joct * 8];
      } else {
        gb[p] = zero8;
      }
    }
    __syncthreads();   // previous iteration's compute done
    #pragma unroll
    for (int p = 0; p < 4; p++) {
      int q = t + p * 256;
      int row = q >> 3, slot = q & 7;
      int st = ((slot ^ (row & 7)) << 3);
      *(us8*)&As[row * 64 + st] = ga[p];
      *(us8*)&Bs[row * 64 + st] = gb[p];
    }
    __syncthreads();
    bf16x8 fah[4], fal[4], fbh[4], fbl[4];
    #pragma unroll
    for (int i = 0; i < 4; i++) {
      int m = wm * 64 + i * 16 + rr;
      int base = m * 64, sw = m & 7;
      fah[i] = *(const bf16x8*)&As[base + ((g ^ sw) << 3)];
      fal[i] = *(const bf16x8*)&As[base + (((4 + g) ^ sw) << 3)];
    }
    #pragma unroll
    for (int j = 0; j < 4; j++) {
      int c = wn * 64 + j * 16 + rr;
      int base = c * 64, sw = c & 7;
      fbh[j] = *(const bf16x8*)&Bs[base + ((g ^ sw) << 3)];
      fbl[j] = *(const bf16x8*)&Bs[base + (((4 + g) ^ sw) << 3)];
    }
    #pragma unroll
    for (int i = 0; i < 4; i++)
      #pragma unroll
      for (int j = 0; j < 4; j++) {
        acc[i][j] = __builtin_amdgcn_mfma_f32_16x16x32_bf16(fah[i], fbh[j], acc[i][j], 0, 0, 0);
        acc[i][j] = __builtin_amdgcn_mfma_f32_16x16x32_bf16(fah[i], fbl[j], acc[i][j], 0, 0, 0);
        acc[i][j] = __builtin_amdgcn_mfma_f32_16x16x32_bf16(fal[i], fbh[j], acc[i][j], 0, 0, 0);
      }
  }
  // epilogue: C[row=(g*4+reg), col=rr] per frag; add db3, guarded store
  #pragma unroll
  for (int j = 0; j < 4; j++) {
    int n = n0 + wn * 64 + j * 16 + rr;
    if (n < NVOCAB) {
      float bias = db3[n];
      #pragma unroll
      for (int i = 0; i < 4; i++) {
        int mb = m0 + wm * 64 + i * 16 + g * 4;
        #pragma unroll
        for (int q2 = 0; q2 < 4; q2++) {
          out[(size_t)(mb + q2) * NVOCAB + n] = acc[i][j][q2] + bias;
        }
      }
    }
  }
}

// --- fallback fp32 logits (previous proven kernel) ---
__global__ __launch_bounds__(256) void k_logits(const float* dw3, const float* db3,
                                                float* out, const float* ws) {
  __shared__ __align__(16) float Asl[16 * 128];
  __shared__ __align__(16) float Bsl[16 * 128];
  int t = threadIdx.x;
  int n0 = blockIdx.x * 128;
  int m0 = blockIdx.y * 128;
  int tx = t & 15, ty = t >> 4;
  const float* h2 = ws + OFF_H2;

  float acc[8][8];
  #pragma unroll
  for (int i = 0; i < 8; i++)
    #pragma unroll
    for (int j = 0; j < 8; j++) acc[i][j] = 0.f;

  int ar = t >> 1, ah = t & 1;
  int bk = t >> 4, bn = (t & 15) * 8;
  bool bval = (n0 + bn) < NVOCAB;

  for (int k0 = 0; k0 < 256; k0 += 16) {
    float4 av0 = *(const float4*)&h2[(m0 + ar) * 256 + k0 + ah * 8];
    float4 av1 = *(const float4*)&h2[(m0 + ar) * 256 + k0 + ah * 8 + 4];
    float4 bv0, bv1;
    if (bval) {
      const float* bp = dw3 + (size_t)(k0 + bk) * NVOCAB + n0 + bn;
      bv0 = *(const float4*)bp;
      bv1 = *(const float4*)(bp + 4);
    } else {
      bv0 = make_float4(0.f, 0.f, 0.f, 0.f);
      bv1 = make_float4(0.f, 0.f, 0.f, 0.f);
    }
    __syncthreads();
    {
      int kb = ah * 8;
      Asl[(kb + 0) * 128 + ar] = av0.x;
      Asl[(kb + 1) * 128 + ar] = av0.y;
      Asl[(kb + 2) * 128 + ar] = av0.z;
      Asl[(kb + 3) * 128 + ar] = av0.w;
      Asl[(kb + 4) * 128 + ar] = av1.x;
      Asl[(kb + 5) * 128 + ar] = av1.y;
      Asl[(kb + 6) * 128 + ar] = av1.z;
      Asl[(kb + 7) * 128 + ar] = av1.w;
      *(float4*)&Bsl[bk * 128 + bn] = bv0;
      *(float4*)&Bsl[bk * 128 + bn + 4] = bv1;
    }
    __syncthreads();
    #pragma unroll
    for (int k = 0; k < 16; k++) {
      float4 a0 = *(const float4*)&Asl[k * 128 + ty * 4];
      float4 a1 = *(const float4*)&Asl[k * 128 + 64 + ty * 4];
      float4 b0 = *(const float4*)&Bsl[k * 128 + tx * 4];
      float4 b1 = *(const float4*)&Bsl[k * 128 + 64 + tx * 4];
      float am[8] = {a0.x, a0.y, a0.z, a0.w, a1.x, a1.y, a1.z, a1.w};
      float bm[8] = {b0.x, b0.y, b0.z, b0.w, b1.x, b1.y, b1.z, b1.w};
      #pragma unroll
      for (int i = 0; i < 8; i++)
        #pragma unroll
        for (int j = 0; j < 8; j++)
          acc[i][j] += am[i] * bm[j];
    }
  }
  #pragma unroll
  for (int jj = 0; jj < 2; jj++) {
    int nb = n0 + jj * 64 + tx * 4;
    if (nb < NVOCAB) {
      float4 bias = *(const float4*)&db3[nb];
      #pragma unroll
      for (int i = 0; i < 8; i++) {
        int m = m0 + (i < 4 ? ty * 4 + i : 64 + ty * 4 + (i - 4));
        float4 o;
        o.x = acc[i][jj * 4 + 0] + bias.x;
        o.y = acc[i][jj * 4 + 1] + bias.y;
        o.z = acc[i][jj * 4 + 2] + bias.z;
        o.w = acc[i][jj * 4 + 3] + bias.w;
        *(float4*)&out[(size_t)m * NVOCAB + nb] = o;
      }
    }
  }
}

extern "C" void kernel_launch(void* const* d_in, const int* in_sizes, int n_in,
                              void* d_out, int out_size, void* d_ws, size_t ws_size,
                              hipStream_t stream) {
  const int*   ids = (const int*)d_in[0];
  const float* emb = (const float*)d_in[1];
  const float* dw1 = (const float*)d_in[2];
  const float* db1 = (const float*)d_in[3];
  const float* lng = (const float*)d_in[4];
  const float* lnb = (const float*)d_in[5];
  const float* dw2 = (const float*)d_in[6];
  const float* db2 = (const float*)d_in[7];
  const float* dw3 = (const float*)d_in[8];
  const float* db3 = (const float*)d_in[9];
  const float* cw1 = (const float*)d_in[10];
  const float* cb1 = (const float*)d_in[11];
  const float* cw2 = (const float*)d_in[12];
  const float* cb2 = (const float*)d_in[13];
  const float* cw3 = (const float*)d_in[14];
  const float* cb3 = (const float*)d_in[15];
  const float* sw1 = (const float*)d_in[16];
  const float* sb1 = (const float*)d_in[17];
  const float* sw2 = (const float*)d_in[18];
  const float* sb2 = (const float*)d_in[19];
  float* out = (float*)d_out;
  float* ws  = (float*)d_ws;

  bool mfma_ok = ws_size >= (size_t)WS_TOTAL_F * sizeof(float);

  hipLaunchKernelGGL(k_prep1, dim3(2), dim3(256), 0, stream, ws);
  hipLaunchKernelGGL(k_prep2, dim3(1024), dim3(256), 0, stream, cw1, dw1, ws);
  hipLaunchKernelGGL(k_spectral, dim3(256), dim3(256), 0, stream, ids, emb, ws);
  hipLaunchKernelGGL(k_concept, dim3(256), dim3(256), 0, stream, cb1, cw2, cb2, cw3, cb3, ws);
  hipLaunchKernelGGL(k_structure, dim3(1), dim3(128), 0, stream, sw1, sb1, sw2, sb2, out, ws);
  hipLaunchKernelGGL(k_decoder, dim3(256), dim3(256), 0, stream, db1, lng, lnb, dw2, db2, ws);
  if (mfma_ok) {
    hipLaunchKernelGGL(k_splitB, dim3(782, 4), dim3(256), 0, stream, dw3, ws);
    hipLaunchKernelGGL(k_splitA, dim3(256), dim3(256), 0, stream, ws);
    hipLaunchKernelGGL(k_logits_mfma, dim3(391, 16), dim3(256), 0, stream, db3, out, ws);
  } else {
    hipLaunchKernelGGL(k_logits, dim3(391, 16), dim3(256), 0, stream, dw3, db3, out, ws);
  }
}

// Round 5
// 864.271 us; speedup vs baseline: 1.0217x; 1.0217x over previous
//
#include <hip/hip_runtime.h>
#include <math.h>

#define NVOCAB 50000
#define NE 256
#define NS 512
#define NB 4
#define NT 2048

// workspace float offsets
#define OFF_G     0
#define OFF_GMAT  256
#define OFF_CW1   (OFF_GMAT + 65536)
#define OFF_DW1   (OFF_CW1 + 65536)
#define OFF_XS    (OFF_DW1 + 131072)
#define OFF_H2    (OFF_XS + 524288)
#define OFF_CA    (OFF_H2 + 524288)
// bf16 split buffers (ushorts packed into float ws):
#define OFF_AH    (OFF_CA + 128)        // h2 hi: 2048*256 ushort = 262144 floats
#define OFF_AL    (OFF_AH + 262144)     // h2 lo
#define OFF_BH    (OFF_AL + 262144)     // dw3^T hi: 50000*256 ushort = 6400000 floats
#define OFF_BL    (OFF_BH + 6400000)    // dw3^T lo
#define WS_TOTAL_F (OFF_BL + 6400000)   // ~58.5 MB

typedef short bf16x8 __attribute__((ext_vector_type(8)));
typedef float f32x4 __attribute__((ext_vector_type(4)));
typedef unsigned short us8 __attribute__((ext_vector_type(8)));

__device__ __forceinline__ float gelu_exact(float x) {
  return 0.5f * x * (1.0f + erff(x * 0.70710678118654752440f));
}

__device__ __forceinline__ unsigned short f2bf(float x) {
  unsigned u = __float_as_uint(x);
  u += 0x7FFFu + ((u >> 16) & 1u);   // round-to-nearest-even
  return (unsigned short)(u >> 16);
}
__device__ __forceinline__ float bf2f(unsigned short h) {
  return __uint_as_float(((unsigned)h) << 16);
}

// --- prep1: spectral kernel g[256] + zero concept accumulator ---
__global__ __launch_bounds__(256) void k_prep1(float* ws) {
  int t = threadIdx.x;
  if (blockIdx.x == 0) {
    float sum = 0.f;
    for (int m = 0; m < 256; m++) {
      int mm = (m <= 128) ? m : (256 - m);
      float c = cosf(1.5f * atanf(logf(4.0f * (float)mm + 1e-6f)));
      int r = (m * t) & 255;
      sum += c * cosf((float)r * (6.283185307179586f / 256.0f));
    }
    ws[OFF_G + t] = sum * (1.0f / 256.0f);
  } else {
    if (t < 128) ws[OFF_CA + t] = 0.0f;
  }
}

// --- prep2: Gmat[d][t] = g[(t-d)&255]; effective (block-summed) cw1/dw1 ---
__global__ __launch_bounds__(256) void k_prep2(const float* cw1, const float* dw1, float* ws) {
  int b = blockIdx.x, t = threadIdx.x;
  if (b < 256) {
    int d = b;
    ws[OFF_GMAT + d * 256 + t] = ws[OFF_G + ((t - d) & 255)];
  } else if (b < 512) {
    int r = b - 256;
    float s = 0.f;
    #pragma unroll
    for (int q = 0; q < 4; q++) s += cw1[(q * 256 + r) * 256 + t];
    ws[OFF_CW1 + r * 256 + t] = s;
  } else {
    int idx = (b - 512) * 256 + t;
    int r = idx >> 9, c = idx & 511;
    float s = 0.f;
    #pragma unroll
    for (int q = 0; q < 4; q++) s += dw1[(q * 256 + r) * 512 + c];
    ws[OFF_DW1 + idx] = s;
  }
}

// --- spectral: xs[i][t] = (sum_d |x[i][d]| * Gmat[d][t]) * sign(x[i][t]) ---
__global__ __launch_bounds__(256) void k_spectral(const int* ids, const float* emb, float* ws) {
  __shared__ __align__(16) float xb[8][256];
  int t = threadIdx.x;
  int i0 = blockIdx.x * 8;
  #pragma unroll
  for (int rr = 0; rr < 8; rr++) {
    int id = ids[i0 + rr];
    xb[rr][t] = emb[id * 256 + t];
  }
  __syncthreads();
  float acc[8] = {0, 0, 0, 0, 0, 0, 0, 0};
  const float* Gm = ws + OFF_GMAT;
  for (int d = 0; d < 256; d += 4) {
    float w0 = Gm[(d + 0) * 256 + t];
    float w1 = Gm[(d + 1) * 256 + t];
    float w2 = Gm[(d + 2) * 256 + t];
    float w3 = Gm[(d + 3) * 256 + t];
    #pragma unroll
    for (int rr = 0; rr < 8; rr++) {
      float4 a4 = *(const float4*)&xb[rr][d];
      acc[rr] += fabsf(a4.x) * w0 + fabsf(a4.y) * w1 + fabsf(a4.z) * w2 + fabsf(a4.w) * w3;
    }
  }
  #pragma unroll
  for (int rr = 0; rr < 8; rr++) {
    float x = xb[rr][t];
    float sg = (x > 0.f) ? 1.f : ((x < 0.f) ? -1.f : 0.f);
    ws[OFF_XS + (i0 + rr) * 256 + t] = acc[rr] * sg;
  }
}

// --- concept recognizer + per-block partial mean into accumulator ---
__global__ __launch_bounds__(256) void k_concept(const float* cb1, const float* cw2, const float* cb2,
                                                 const float* cw3, const float* cb3, float* ws) {
  __shared__ __align__(16) float xs_s[8][256];
  __shared__ __align__(16) float c1s[8][256];
  __shared__ float c2s[8][64];
  __shared__ float c3s[8][32];
  int t = threadIdx.x;
  int i0 = blockIdx.x * 8;
  #pragma unroll
  for (int rr = 0; rr < 8; rr++) xs_s[rr][t] = ws[OFF_XS + (i0 + rr) * 256 + t];
  __syncthreads();
  const float* cw1eff = ws + OFF_CW1;
  float acc[8] = {0, 0, 0, 0, 0, 0, 0, 0};
  for (int d = 0; d < 256; d += 4) {
    float w0 = cw1eff[(d + 0) * 256 + t];
    float w1 = cw1eff[(d + 1) * 256 + t];
    float w2 = cw1eff[(d + 2) * 256 + t];
    float w3 = cw1eff[(d + 3) * 256 + t];
    #pragma unroll
    for (int rr = 0; rr < 8; rr++) {
      float4 a4 = *(const float4*)&xs_s[rr][d];
      acc[rr] += a4.x * w0 + a4.y * w1 + a4.z * w2 + a4.w * w3;
    }
  }
  float b1v = cb1[t];
  #pragma unroll
  for (int rr = 0; rr < 8; rr++) c1s[rr][t] = fmaxf(acc[rr] + b1v, 0.f);
  __syncthreads();
  {
    int e = t & 63, grp = t >> 6;
    float a0 = 0.f, a1 = 0.f;
    for (int d = 0; d < 256; d++) {
      float w = cw2[d * 64 + e];
      a0 += c1s[grp * 2 + 0][d] * w;
      a1 += c1s[grp * 2 + 1][d] * w;
    }
    float b2v = cb2[e];
    c2s[grp * 2 + 0][e] = fmaxf(a0 + b2v, 0.f);
    c2s[grp * 2 + 1][e] = fmaxf(a1 + b2v, 0.f);
  }
  __syncthreads();
  {
    int v = t & 31, grp = t >> 5;
    float a = 0.f;
    for (int d = 0; d < 64; d++) a += c2s[grp][d] * cw3[d * 32 + v];
    c3s[grp][v] = a + cb3[v];
  }
  __syncthreads();
  if (t < 32) {
    float s = 0.f;
    #pragma unroll
    for (int rr = 0; rr < 8; rr++) s += c3s[rr][t];
    int bb = i0 >> 9;
    atomicAdd(ws + OFF_CA + bb * 32 + t, s * (1.0f / 512.0f));
  }
}

// --- structure generator (tiny) + emit concept_vector ---
__global__ __launch_bounds__(128) void k_structure(const float* sw1, const float* sb1,
                                                   const float* sw2, const float* sb2,
                                                   float* out, const float* ws) {
  __shared__ float cv[4][32];
  __shared__ float s1[4][16];
  int t = threadIdx.x;
  {
    int b = t >> 5, j = t & 31;
    float v = ws[OFF_CA + t];
    cv[b][j] = v;
    out[102400000 + t] = v;
  }
  __syncthreads();
  if (t < 64) {
    int b = t >> 4, e = t & 15;
    float a = sb1[e];
    for (int d = 0; d < 32; d++) a += cv[b][d] * sw1[d * 16 + e];
    s1[b][e] = fmaxf(a, 0.f);
  }
  __syncthreads();
  if (t < 32) {
    int b = t >> 3, e = t & 7;
    float a = sb2[e];
    for (int d = 0; d < 16; d++) a += s1[b][d] * sw2[d * 8 + e];
    out[102400128 + t] = 1.0f / (1.0f + expf(-a));
  }
}

// --- decoder mid: h1 = gelu(xs@DW1eff+db1); LN; h2 = gelu(h1@dw2+db2) ---
// emit_split!=0: also write bf16 hi/lo split of h2 (fused splitA)
__global__ __launch_bounds__(256) void k_decoder(const float* db1, const float* lng, const float* lnb,
                                                 const float* dw2, const float* db2, float* ws,
                                                 int emit_split) {
  __shared__ __align__(16) float xs_s[8][256];
  __shared__ __align__(16) float h1s[8][512];
  __shared__ float mu_s[8], rs_s[8];
  int t = threadIdx.x;
  int i0 = blockIdx.x * 8;
  #pragma unroll
  for (int rr = 0; rr < 8; rr++) xs_s[rr][t] = ws[OFF_XS + (i0 + rr) * 256 + t];
  __syncthreads();
  const float* dw1eff = ws + OFF_DW1;
  float a1[8] = {0, 0, 0, 0, 0, 0, 0, 0};
  float a2[8] = {0, 0, 0, 0, 0, 0, 0, 0};
  for (int d = 0; d < 256; d += 2) {
    float wa0 = dw1eff[(d + 0) * 512 + t];
    float wb0 = dw1eff[(d + 0) * 512 + t + 256];
    float wa1 = dw1eff[(d + 1) * 512 + t];
    float wb1 = dw1eff[(d + 1) * 512 + t + 256];
    #pragma unroll
    for (int rr = 0; rr < 8; rr++) {
      float2 x2 = *(const float2*)&xs_s[rr][d];
      a1[rr] += x2.x * wa0 + x2.y * wa1;
      a2[rr] += x2.x * wb0 + x2.y * wb1;
    }
  }
  float ba = db1[t], bb = db1[t + 256];
  #pragma unroll
  for (int rr = 0; rr < 8; rr++) {
    h1s[rr][t]       = gelu_exact(a1[rr] + ba);
    h1s[rr][t + 256] = gelu_exact(a2[rr] + bb);
  }
  __syncthreads();
  {
    int rr = t >> 5, q = t & 31;
    float sum = 0.f, sq = 0.f;
    for (int j = q; j < 512; j += 32) {
      float v = h1s[rr][j];
      sum += v; sq += v * v;
    }
    #pragma unroll
    for (int off = 16; off >= 1; off >>= 1) {
      sum += __shfl_down(sum, off, 32);
      sq  += __shfl_down(sq, off, 32);
    }
    if (q == 0) {
      float mu = sum * (1.0f / 512.0f);
      float var = sq * (1.0f / 512.0f) - mu * mu;
      mu_s[rr] = mu;
      rs_s[rr] = rsqrtf(var + 1e-5f);
    }
  }
  __syncthreads();
  {
    float ga = lng[t], bba = lnb[t], gb = lng[t + 256], bbb = lnb[t + 256];
    #pragma unroll
    for (int rr = 0; rr < 8; rr++) {
      float m = mu_s[rr], r = rs_s[rr];
      h1s[rr][t]       = (h1s[rr][t]       - m) * r * ga + bba;
      h1s[rr][t + 256] = (h1s[rr][t + 256] - m) * r * gb + bbb;
    }
  }
  __syncthreads();
  float acc[8] = {0, 0, 0, 0, 0, 0, 0, 0};
  for (int d = 0; d < 512; d += 2) {
    float w0 = dw2[(d + 0) * 256 + t];
    float w1 = dw2[(d + 1) * 256 + t];
    #pragma unroll
    for (int rr = 0; rr < 8; rr++) {
      float2 h2v = *(const float2*)&h1s[rr][d];
      acc[rr] += h2v.x * w0 + h2v.y * w1;
    }
  }
  float b2v = db2[t];
  unsigned short* Ahp = (unsigned short*)(ws + OFF_AH);
  unsigned short* Alp = (unsigned short*)(ws + OFF_AL);
  #pragma unroll
  for (int rr = 0; rr < 8; rr++) {
    float v = gelu_exact(acc[rr] + b2v);
    ws[OFF_H2 + (i0 + rr) * 256 + t] = v;
    if (emit_split) {
      unsigned short hb = f2bf(v);
      Ahp[(i0 + rr) * 256 + t] = hb;
      Alp[(i0 + rr) * 256 + t] = f2bf(v - bf2f(hb));
    }
  }
}

// --- splitB: dw3 fp32 [256][50000] -> Bh, Bl bf16 transposed [50000][256] ---
__global__ __launch_bounds__(256) void k_splitB(const float* dw3, float* ws) {
  __shared__ float tile[64][65];
  int t = threadIdx.x;
  int n0 = blockIdx.x * 64;       // 782 blocks, tail block has 16 valid cols
  int k0 = blockIdx.y * 64;       // 4 blocks
  int tc = t & 15, tr = t >> 4;
  #pragma unroll
  for (int p = 0; p < 4; p++) {
    int k = k0 + tr + p * 16;
    int n = n0 + tc * 4;
    float4 v = make_float4(0.f, 0.f, 0.f, 0.f);
    if (n < NVOCAB) v = *(const float4*)&dw3[(size_t)k * NVOCAB + n];  // 50000%4==0
    tile[tr + p * 16][tc * 4 + 0] = v.x;
    tile[tr + p * 16][tc * 4 + 1] = v.y;
    tile[tr + p * 16][tc * 4 + 2] = v.z;
    tile[tr + p * 16][tc * 4 + 3] = v.w;
  }
  __syncthreads();
  int nl = t >> 2, kq = (t & 3) * 16;
  int n = n0 + nl;
  if (n < NVOCAB) {
    unsigned short* Bh = (unsigned short*)(ws + OFF_BH);
    unsigned short* Bl = (unsigned short*)(ws + OFF_BL);
    us8 h0, h1, l0, l1;
    #pragma unroll
    for (int i = 0; i < 8; i++) {
      float x = tile[kq + i][nl];
      unsigned short hb = f2bf(x);
      h0[i] = (short)hb;
      l0[i] = (short)f2bf(x - bf2f(hb));
    }
    #pragma unroll
    for (int i = 0; i < 8; i++) {
      float x = tile[kq + 8 + i][nl];
      unsigned short hb = f2bf(x);
      h1[i] = (short)hb;
      l1[i] = (short)f2bf(x - bf2f(hb));
    }
    size_t base = (size_t)n * 256 + k0 + kq;
    *(us8*)&Bh[base] = h0;
    *(us8*)&Bh[base + 8] = h1;
    *(us8*)&Bl[base] = l0;
    *(us8*)&Bl[base + 8] = l1;
  }
}

// --- logits via MFMA: C = (Ah+Al)(Bh+Bl) ~ AhBh + AhBl + AlBh, fp32 accum ---
// 128x128 tile, BK=32, 4 waves (2x2), 4x4 frags of 16x16x32 per wave.
// Double-buffered LDS (2-phase), XCD-chunked 1D grid (m-tile innermost),
// swapped mfma operands -> float4 nontemporal stores.
__global__ __launch_bounds__(256, 2) void k_logits_mfma(const float* db3, float* out, const float* ws) {
  __shared__ __align__(16) unsigned short As[2][128 * 64];
  __shared__ __align__(16) unsigned short Bs[2][128 * 64];
  const unsigned short* Ah = (const unsigned short*)(ws + OFF_AH);
  const unsigned short* Al = (const unsigned short*)(ws + OFF_AL);
  const unsigned short* Bh = (const unsigned short*)(ws + OFF_BH);
  const unsigned short* Bl = (const unsigned short*)(ws + OFF_BL);
  int t = threadIdx.x;
  // XCD-chunked mapping: 6256 = 8 XCDs * 782; within an XCD, m-tile cycles
  // fastest so 16 consecutive blocks share one B panel (L2-resident) and the
  // whole A (2 MB) stays in each XCD's L2.
  int bid = blockIdx.x;
  int work = ((bid & 7) * 782) + (bid >> 3);
  int m0 = (work & 15) << 7;     // 16 m-tiles
  int n0 = (work >> 4) << 7;     // 391 n-tiles
  int lane = t & 63;
  int w = t >> 6;
  int wm = w >> 1, wn = w & 1;
  int rr = lane & 15, g = lane >> 4;

  f32x4 acc[4][4];
  #pragma unroll
  for (int i = 0; i < 4; i++)
    #pragma unroll
    for (int j = 0; j < 4; j++)
      acc[i][j] = (f32x4){0.f, 0.f, 0.f, 0.f};

  const us8 zero8 = {0, 0, 0, 0, 0, 0, 0, 0};
  us8 ga[4], gb[4];

  auto LOADT = [&](int kk) {
    int k0 = kk * 32;
    #pragma unroll
    for (int p = 0; p < 4; p++) {
      int q = t + p * 256;            // 0..1023
      int row = q >> 3, slot = q & 7; // row 0..127, slot 0..7
      int joct = slot & 3;
      const unsigned short* srcA = (slot < 4) ? Ah : Al;
      ga[p] = *(const us8*)&srcA[(size_t)(m0 + row) * 256 + k0 + joct * 8];
      int n = n0 + row;
      if (n < NVOCAB) {
        const unsigned short* srcB = (slot < 4) ? Bh : Bl;
        gb[p] = *(const us8*)&srcB[(size_t)n * 256 + k0 + joct * 8];
      } else {
        gb[p] = zero8;
      }
    }
  };
  auto STORET = [&](int b) {
    #pragma unroll
    for (int p = 0; p < 4; p++) {
      int q = t + p * 256;
      int row = q >> 3, slot = q & 7;
      int st = ((slot ^ (row & 7)) << 3);
      *(us8*)&As[b][row * 64 + st] = ga[p];
      *(us8*)&Bs[b][row * 64 + st] = gb[p];
    }
  };

  LOADT(0);
  STORET(0);
  __syncthreads();

  #pragma unroll 2
  for (int kk = 0; kk < 8; kk++) {
    if (kk < 7) LOADT(kk + 1);         // prefetch next tile (hides HBM latency under MFMA)
    const unsigned short* Ab = As[kk & 1];
    const unsigned short* Bb = Bs[kk & 1];
    bf16x8 fah[4], fal[4], fbh[4], fbl[4];
    #pragma unroll
    for (int i = 0; i < 4; i++) {
      int m = wm * 64 + i * 16 + rr;
      int base = m * 64, sw = m & 7;
      fah[i] = *(const bf16x8*)&Ab[base + ((g ^ sw) << 3)];
      fal[i] = *(const bf16x8*)&Ab[base + (((4 + g) ^ sw) << 3)];
    }
    #pragma unroll
    for (int j = 0; j < 4; j++) {
      int c = wn * 64 + j * 16 + rr;
      int base = c * 64, sw = c & 7;
      fbh[j] = *(const bf16x8*)&Bb[base + ((g ^ sw) << 3)];
      fbl[j] = *(const bf16x8*)&Bb[base + (((4 + g) ^ sw) << 3)];
    }
    // swapped operands: acc[i][j] holds C[m = ..i..+rr][n = ..j..+g*4+reg]
    #pragma unroll
    for (int i = 0; i < 4; i++)
      #pragma unroll
      for (int j = 0; j < 4; j++) {
        acc[i][j] = __builtin_amdgcn_mfma_f32_16x16x32_bf16(fbh[j], fah[i], acc[i][j], 0, 0, 0);
        acc[i][j] = __builtin_amdgcn_mfma_f32_16x16x32_bf16(fbl[j], fah[i], acc[i][j], 0, 0, 0);
        acc[i][j] = __builtin_amdgcn_mfma_f32_16x16x32_bf16(fbh[j], fal[i], acc[i][j], 0, 0, 0);
      }
    if (kk < 7) {
      STORET((kk + 1) & 1);
      __syncthreads();
    }
  }

  // epilogue: per (i,j) each lane holds 4 consecutive n for one m -> float4 nt stores
  #pragma unroll
  for (int i = 0; i < 4; i++) {
    int m = m0 + wm * 64 + i * 16 + rr;
    #pragma unroll
    for (int j = 0; j < 4; j++) {
      int nb = n0 + wn * 64 + j * 16 + g * 4;
      if (nb < NVOCAB) {
        f32x4 bias = *(const f32x4*)&db3[nb];
        f32x4 o = acc[i][j] + bias;
        __builtin_nontemporal_store(o, (f32x4*)(out + (size_t)m * NVOCAB + nb));
      }
    }
  }
}

// --- fallback fp32 logits (previous proven kernel) ---
__global__ __launch_bounds__(256) void k_logits(const float* dw3, const float* db3,
                                                float* out, const float* ws) {
  __shared__ __align__(16) float Asl[16 * 128];
  __shared__ __align__(16) float Bsl[16 * 128];
  int t = threadIdx.x;
  int n0 = blockIdx.x * 128;
  int m0 = blockIdx.y * 128;
  int tx = t & 15, ty = t >> 4;
  const float* h2 = ws + OFF_H2;

  float acc[8][8];
  #pragma unroll
  for (int i = 0; i < 8; i++)
    #pragma unroll
    for (int j = 0; j < 8; j++) acc[i][j] = 0.f;

  int ar = t >> 1, ah = t & 1;
  int bk = t >> 4, bn = (t & 15) * 8;
  bool bval = (n0 + bn) < NVOCAB;

  for (int k0 = 0; k0 < 256; k0 += 16) {
    float4 av0 = *(const float4*)&h2[(m0 + ar) * 256 + k0 + ah * 8];
    float4 av1 = *(const float4*)&h2[(m0 + ar) * 256 + k0 + ah * 8 + 4];
    float4 bv0, bv1;
    if (bval) {
      const float* bp = dw3 + (size_t)(k0 + bk) * NVOCAB + n0 + bn;
      bv0 = *(const float4*)bp;
      bv1 = *(const float4*)(bp + 4);
    } else {
      bv0 = make_float4(0.f, 0.f, 0.f, 0.f);
      bv1 = make_float4(0.f, 0.f, 0.f, 0.f);
    }
    __syncthreads();
    {
      int kb = ah * 8;
      Asl[(kb + 0) * 128 + ar] = av0.x;
      Asl[(kb + 1) * 128 + ar] = av0.y;
      Asl[(kb + 2) * 128 + ar] = av0.z;
      Asl[(kb + 3) * 128 + ar] = av0.w;
      Asl[(kb + 4) * 128 + ar] = av1.x;
      Asl[(kb + 5) * 128 + ar] = av1.y;
      Asl[(kb + 6) * 128 + ar] = av1.z;
      Asl[(kb + 7) * 128 + ar] = av1.w;
      *(float4*)&Bsl[bk * 128 + bn] = bv0;
      *(float4*)&Bsl[bk * 128 + bn + 4] = bv1;
    }
    __syncthreads();
    #pragma unroll
    for (int k = 0; k < 16; k++) {
      float4 a0 = *(const float4*)&Asl[k * 128 + ty * 4];
      float4 a1 = *(const float4*)&Asl[k * 128 + 64 + ty * 4];
      float4 b0 = *(const float4*)&Bsl[k * 128 + tx * 4];
      float4 b1 = *(const float4*)&Bsl[k * 128 + 64 + tx * 4];
      float am[8] = {a0.x, a0.y, a0.z, a0.w, a1.x, a1.y, a1.z, a1.w};
      float bm[8] = {b0.x, b0.y, b0.z, b0.w, b1.x, b1.y, b1.z, b1.w};
      #pragma unroll
      for (int i = 0; i < 8; i++)
        #pragma unroll
        for (int j = 0; j < 8; j++)
          acc[i][j] += am[i] * bm[j];
    }
  }
  #pragma unroll
  for (int jj = 0; jj < 2; jj++) {
    int nb = n0 + jj * 64 + tx * 4;
    if (nb < NVOCAB) {
      float4 bias = *(const float4*)&db3[nb];
      #pragma unroll
      for (int i = 0; i < 8; i++) {
        int m = m0 + (i < 4 ? ty * 4 + i : 64 + ty * 4 + (i - 4));
        float4 o;
        o.x = acc[i][jj * 4 + 0] + bias.x;
        o.y = acc[i][jj * 4 + 1] + bias.y;
        o.z = acc[i][jj * 4 + 2] + bias.z;
        o.w = acc[i][jj * 4 + 3] + bias.w;
        *(float4*)&out[(size_t)m * NVOCAB + nb] = o;
      }
    }
  }
}

extern "C" void kernel_launch(void* const* d_in, const int* in_sizes, int n_in,
                              void* d_out, int out_size, void* d_ws, size_t ws_size,
                              hipStream_t stream) {
  const int*   ids = (const int*)d_in[0];
  const float* emb = (const float*)d_in[1];
  const float* dw1 = (const float*)d_in[2];
  const float* db1 = (const float*)d_in[3];
  const float* lng = (const float*)d_in[4];
  const float* lnb = (const float*)d_in[5];
  const float* dw2 = (const float*)d_in[6];
  const float* db2 = (const float*)d_in[7];
  const float* dw3 = (const float*)d_in[8];
  const float* db3 = (const float*)d_in[9];
  const float* cw1 = (const float*)d_in[10];
  const float* cb1 = (const float*)d_in[11];
  const float* cw2 = (const float*)d_in[12];
  const float* cb2 = (const float*)d_in[13];
  const float* cw3 = (const float*)d_in[14];
  const float* cb3 = (const float*)d_in[15];
  const float* sw1 = (const float*)d_in[16];
  const float* sb1 = (const float*)d_in[17];
  const float* sw2 = (const float*)d_in[18];
  const float* sb2 = (const float*)d_in[19];
  float* out = (float*)d_out;
  float* ws  = (float*)d_ws;

  bool mfma_ok = ws_size >= (size_t)WS_TOTAL_F * sizeof(float);

  hipLaunchKernelGGL(k_prep1, dim3(2), dim3(256), 0, stream, ws);
  hipLaunchKernelGGL(k_prep2, dim3(1024), dim3(256), 0, stream, cw1, dw1, ws);
  if (mfma_ok) hipLaunchKernelGGL(k_splitB, dim3(782, 4), dim3(256), 0, stream, dw3, ws);
  hipLaunchKernelGGL(k_spectral, dim3(256), dim3(256), 0, stream, ids, emb, ws);
  hipLaunchKernelGGL(k_concept, dim3(256), dim3(256), 0, stream, cb1, cw2, cb2, cw3, cb3, ws);
  hipLaunchKernelGGL(k_structure, dim3(1), dim3(128), 0, stream, sw1, sb1, sw2, sb2, out, ws);
  hipLaunchKernelGGL(k_decoder, dim3(256), dim3(256), 0, stream, db1, lng, lnb, dw2, db2, ws,
                     mfma_ok ? 1 : 0);
  if (mfma_ok) {
    hipLaunchKernelGGL(k_logits_mfma, dim3(6256), dim3(256), 0, stream, db3, out, ws);
  } else {
    hipLaunchKernelGGL(k_logits, dim3(391, 16), dim3(256), 0, stream, dw3, db3, out, ws);
  }
}

// Round 6
// 862.471 us; speedup vs baseline: 1.0239x; 1.0021x over previous
//
#include <hip/hip_runtime.h>
#include <math.h>

#define NVOCAB 50000
#define NE 256
#define NS 512
#define NB 4
#define NT 2048

// workspace float offsets
#define OFF_G     0
#define OFF_GMAT  256
#define OFF_CW1   (OFF_GMAT + 65536)
#define OFF_DW1   (OFF_CW1 + 65536)
#define OFF_XS    (OFF_DW1 + 131072)
#define OFF_H2    (OFF_XS + 524288)
#define OFF_CA    (OFF_H2 + 524288)
// bf16 split buffers (ushorts packed into float ws):
#define OFF_AH    (OFF_CA + 128)        // h2 hi: 2048*256 ushort = 262144 floats
#define OFF_AL    (OFF_AH + 262144)     // h2 lo
#define OFF_BH    (OFF_AL + 262144)     // dw3^T hi: 50000*256 ushort = 6400000 floats
#define OFF_BL    (OFF_BH + 6400000)    // dw3^T lo
#define WS_TOTAL_F (OFF_BL + 6400000)   // ~58.5 MB

typedef short bf16x8 __attribute__((ext_vector_type(8)));
typedef float f32x4 __attribute__((ext_vector_type(4)));
typedef unsigned short us8 __attribute__((ext_vector_type(8)));

// direct global->LDS DMA (16B per lane per call); LDS dest is wave-uniform
// base + lane*16, global src is per-lane (pre-swizzled to match the LDS read
// swizzle -- m173 pattern).
#define GLOAD_LDS16(g, l) \
  __builtin_amdgcn_global_load_lds((const __attribute__((address_space(1))) void*)(g), \
                                   (__attribute__((address_space(3))) void*)(l), 16, 0, 0)

__device__ __forceinline__ float gelu_exact(float x) {
  return 0.5f * x * (1.0f + erff(x * 0.70710678118654752440f));
}

__device__ __forceinline__ unsigned short f2bf(float x) {
  unsigned u = __float_as_uint(x);
  u += 0x7FFFu + ((u >> 16) & 1u);   // round-to-nearest-even
  return (unsigned short)(u >> 16);
}
__device__ __forceinline__ float bf2f(unsigned short h) {
  return __uint_as_float(((unsigned)h) << 16);
}

// --- prep1: spectral kernel g[256] + zero concept accumulator ---
__global__ __launch_bounds__(256) void k_prep1(float* ws) {
  int t = threadIdx.x;
  if (blockIdx.x == 0) {
    float sum = 0.f;
    for (int m = 0; m < 256; m++) {
      int mm = (m <= 128) ? m : (256 - m);
      float c = cosf(1.5f * atanf(logf(4.0f * (float)mm + 1e-6f)));
      int r = (m * t) & 255;
      sum += c * cosf((float)r * (6.283185307179586f / 256.0f));
    }
    ws[OFF_G + t] = sum * (1.0f / 256.0f);
  } else {
    if (t < 128) ws[OFF_CA + t] = 0.0f;
  }
}

// --- prep2: Gmat[d][t] = g[(t-d)&255]; effective (block-summed) cw1/dw1 ---
__global__ __launch_bounds__(256) void k_prep2(const float* cw1, const float* dw1, float* ws) {
  int b = blockIdx.x, t = threadIdx.x;
  if (b < 256) {
    int d = b;
    ws[OFF_GMAT + d * 256 + t] = ws[OFF_G + ((t - d) & 255)];
  } else if (b < 512) {
    int r = b - 256;
    float s = 0.f;
    #pragma unroll
    for (int q = 0; q < 4; q++) s += cw1[(q * 256 + r) * 256 + t];
    ws[OFF_CW1 + r * 256 + t] = s;
  } else {
    int idx = (b - 512) * 256 + t;
    int r = idx >> 9, c = idx & 511;
    float s = 0.f;
    #pragma unroll
    for (int q = 0; q < 4; q++) s += dw1[(q * 256 + r) * 512 + c];
    ws[OFF_DW1 + idx] = s;
  }
}

// --- spectral: xs[i][t] = (sum_d |x[i][d]| * Gmat[d][t]) * sign(x[i][t]) ---
__global__ __launch_bounds__(256) void k_spectral(const int* ids, const float* emb, float* ws) {
  __shared__ __align__(16) float xb[8][256];
  int t = threadIdx.x;
  int i0 = blockIdx.x * 8;
  #pragma unroll
  for (int rr = 0; rr < 8; rr++) {
    int id = ids[i0 + rr];
    xb[rr][t] = emb[id * 256 + t];
  }
  __syncthreads();
  float acc[8] = {0, 0, 0, 0, 0, 0, 0, 0};
  const float* Gm = ws + OFF_GMAT;
  for (int d = 0; d < 256; d += 4) {
    float w0 = Gm[(d + 0) * 256 + t];
    float w1 = Gm[(d + 1) * 256 + t];
    float w2 = Gm[(d + 2) * 256 + t];
    float w3 = Gm[(d + 3) * 256 + t];
    #pragma unroll
    for (int rr = 0; rr < 8; rr++) {
      float4 a4 = *(const float4*)&xb[rr][d];
      acc[rr] += fabsf(a4.x) * w0 + fabsf(a4.y) * w1 + fabsf(a4.z) * w2 + fabsf(a4.w) * w3;
    }
  }
  #pragma unroll
  for (int rr = 0; rr < 8; rr++) {
    float x = xb[rr][t];
    float sg = (x > 0.f) ? 1.f : ((x < 0.f) ? -1.f : 0.f);
    ws[OFF_XS + (i0 + rr) * 256 + t] = acc[rr] * sg;
  }
}

// --- concept recognizer + per-block partial mean into accumulator ---
__global__ __launch_bounds__(256) void k_concept(const float* cb1, const float* cw2, const float* cb2,
                                                 const float* cw3, const float* cb3, float* ws) {
  __shared__ __align__(16) float xs_s[8][256];
  __shared__ __align__(16) float c1s[8][256];
  __shared__ float c2s[8][64];
  __shared__ float c3s[8][32];
  int t = threadIdx.x;
  int i0 = blockIdx.x * 8;
  #pragma unroll
  for (int rr = 0; rr < 8; rr++) xs_s[rr][t] = ws[OFF_XS + (i0 + rr) * 256 + t];
  __syncthreads();
  const float* cw1eff = ws + OFF_CW1;
  float acc[8] = {0, 0, 0, 0, 0, 0, 0, 0};
  for (int d = 0; d < 256; d += 4) {
    float w0 = cw1eff[(d + 0) * 256 + t];
    float w1 = cw1eff[(d + 1) * 256 + t];
    float w2 = cw1eff[(d + 2) * 256 + t];
    float w3 = cw1eff[(d + 3) * 256 + t];
    #pragma unroll
    for (int rr = 0; rr < 8; rr++) {
      float4 a4 = *(const float4*)&xs_s[rr][d];
      acc[rr] += a4.x * w0 + a4.y * w1 + a4.z * w2 + a4.w * w3;
    }
  }
  float b1v = cb1[t];
  #pragma unroll
  for (int rr = 0; rr < 8; rr++) c1s[rr][t] = fmaxf(acc[rr] + b1v, 0.f);
  __syncthreads();
  {
    int e = t & 63, grp = t >> 6;
    float a0 = 0.f, a1 = 0.f;
    for (int d = 0; d < 256; d++) {
      float w = cw2[d * 64 + e];
      a0 += c1s[grp * 2 + 0][d] * w;
      a1 += c1s[grp * 2 + 1][d] * w;
    }
    float b2v = cb2[e];
    c2s[grp * 2 + 0][e] = fmaxf(a0 + b2v, 0.f);
    c2s[grp * 2 + 1][e] = fmaxf(a1 + b2v, 0.f);
  }
  __syncthreads();
  {
    int v = t & 31, grp = t >> 5;
    float a = 0.f;
    for (int d = 0; d < 64; d++) a += c2s[grp][d] * cw3[d * 32 + v];
    c3s[grp][v] = a + cb3[v];
  }
  __syncthreads();
  if (t < 32) {
    float s = 0.f;
    #pragma unroll
    for (int rr = 0; rr < 8; rr++) s += c3s[rr][t];
    int bb = i0 >> 9;
    atomicAdd(ws + OFF_CA + bb * 32 + t, s * (1.0f / 512.0f));
  }
}

// --- structure generator (tiny) + emit concept_vector ---
__global__ __launch_bounds__(128) void k_structure(const float* sw1, const float* sb1,
                                                   const float* sw2, const float* sb2,
                                                   float* out, const float* ws) {
  __shared__ float cv[4][32];
  __shared__ float s1[4][16];
  int t = threadIdx.x;
  {
    int b = t >> 5, j = t & 31;
    float v = ws[OFF_CA + t];
    cv[b][j] = v;
    out[102400000 + t] = v;
  }
  __syncthreads();
  if (t < 64) {
    int b = t >> 4, e = t & 15;
    float a = sb1[e];
    for (int d = 0; d < 32; d++) a += cv[b][d] * sw1[d * 16 + e];
    s1[b][e] = fmaxf(a, 0.f);
  }
  __syncthreads();
  if (t < 32) {
    int b = t >> 3, e = t & 7;
    float a = sb2[e];
    for (int d = 0; d < 16; d++) a += s1[b][d] * sw2[d * 8 + e];
    out[102400128 + t] = 1.0f / (1.0f + expf(-a));
  }
}

// --- decoder mid: h1 = gelu(xs@DW1eff+db1); LN; h2 = gelu(h1@dw2+db2) ---
// emit_split!=0: also write bf16 hi/lo split of h2 (fused splitA)
__global__ __launch_bounds__(256) void k_decoder(const float* db1, const float* lng, const float* lnb,
                                                 const float* dw2, const float* db2, float* ws,
                                                 int emit_split) {
  __shared__ __align__(16) float xs_s[8][256];
  __shared__ __align__(16) float h1s[8][512];
  __shared__ float mu_s[8], rs_s[8];
  int t = threadIdx.x;
  int i0 = blockIdx.x * 8;
  #pragma unroll
  for (int rr = 0; rr < 8; rr++) xs_s[rr][t] = ws[OFF_XS + (i0 + rr) * 256 + t];
  __syncthreads();
  const float* dw1eff = ws + OFF_DW1;
  float a1[8] = {0, 0, 0, 0, 0, 0, 0, 0};
  float a2[8] = {0, 0, 0, 0, 0, 0, 0, 0};
  for (int d = 0; d < 256; d += 2) {
    float wa0 = dw1eff[(d + 0) * 512 + t];
    float wb0 = dw1eff[(d + 0) * 512 + t + 256];
    float wa1 = dw1eff[(d + 1) * 512 + t];
    float wb1 = dw1eff[(d + 1) * 512 + t + 256];
    #pragma unroll
    for (int rr = 0; rr < 8; rr++) {
      float2 x2 = *(const float2*)&xs_s[rr][d];
      a1[rr] += x2.x * wa0 + x2.y * wa1;
      a2[rr] += x2.x * wb0 + x2.y * wb1;
    }
  }
  float ba = db1[t], bb = db1[t + 256];
  #pragma unroll
  for (int rr = 0; rr < 8; rr++) {
    h1s[rr][t]       = gelu_exact(a1[rr] + ba);
    h1s[rr][t + 256] = gelu_exact(a2[rr] + bb);
  }
  __syncthreads();
  {
    int rr = t >> 5, q = t & 31;
    float sum = 0.f, sq = 0.f;
    for (int j = q; j < 512; j += 32) {
      float v = h1s[rr][j];
      sum += v; sq += v * v;
    }
    #pragma unroll
    for (int off = 16; off >= 1; off >>= 1) {
      sum += __shfl_down(sum, off, 32);
      sq  += __shfl_down(sq, off, 32);
    }
    if (q == 0) {
      float mu = sum * (1.0f / 512.0f);
      float var = sq * (1.0f / 512.0f) - mu * mu;
      mu_s[rr] = mu;
      rs_s[rr] = rsqrtf(var + 1e-5f);
    }
  }
  __syncthreads();
  {
    float ga = lng[t], bba = lnb[t], gb = lng[t + 256], bbb = lnb[t + 256];
    #pragma unroll
    for (int rr = 0; rr < 8; rr++) {
      float m = mu_s[rr], r = rs_s[rr];
      h1s[rr][t]       = (h1s[rr][t]       - m) * r * ga + bba;
      h1s[rr][t + 256] = (h1s[rr][t + 256] - m) * r * gb + bbb;
    }
  }
  __syncthreads();
  float acc[8] = {0, 0, 0, 0, 0, 0, 0, 0};
  for (int d = 0; d < 512; d += 2) {
    float w0 = dw2[(d + 0) * 256 + t];
    float w1 = dw2[(d + 1) * 256 + t];
    #pragma unroll
    for (int rr = 0; rr < 8; rr++) {
      float2 h2v = *(const float2*)&h1s[rr][d];
      acc[rr] += h2v.x * w0 + h2v.y * w1;
    }
  }
  float b2v = db2[t];
  unsigned short* Ahp = (unsigned short*)(ws + OFF_AH);
  unsigned short* Alp = (unsigned short*)(ws + OFF_AL);
  #pragma unroll
  for (int rr = 0; rr < 8; rr++) {
    float v = gelu_exact(acc[rr] + b2v);
    ws[OFF_H2 + (i0 + rr) * 256 + t] = v;
    if (emit_split) {
      unsigned short hb = f2bf(v);
      Ahp[(i0 + rr) * 256 + t] = hb;
      Alp[(i0 + rr) * 256 + t] = f2bf(v - bf2f(hb));
    }
  }
}

// --- splitB: dw3 fp32 [256][50000] -> Bh, Bl bf16 transposed [50000][256] ---
__global__ __launch_bounds__(256) void k_splitB(const float* dw3, float* ws) {
  __shared__ float tile[64][65];
  int t = threadIdx.x;
  int n0 = blockIdx.x * 64;       // 782 blocks, tail block has 16 valid cols
  int k0 = blockIdx.y * 64;       // 4 blocks
  int tc = t & 15, tr = t >> 4;
  #pragma unroll
  for (int p = 0; p < 4; p++) {
    int k = k0 + tr + p * 16;
    int n = n0 + tc * 4;
    float4 v = make_float4(0.f, 0.f, 0.f, 0.f);
    if (n < NVOCAB) v = *(const float4*)&dw3[(size_t)k * NVOCAB + n];  // 50000%4==0
    tile[tr + p * 16][tc * 4 + 0] = v.x;
    tile[tr + p * 16][tc * 4 + 1] = v.y;
    tile[tr + p * 16][tc * 4 + 2] = v.z;
    tile[tr + p * 16][tc * 4 + 3] = v.w;
  }
  __syncthreads();
  int nl = t >> 2, kq = (t & 3) * 16;
  int n = n0 + nl;
  if (n < NVOCAB) {
    unsigned short* Bh = (unsigned short*)(ws + OFF_BH);
    unsigned short* Bl = (unsigned short*)(ws + OFF_BL);
    us8 h0, h1, l0, l1;
    #pragma unroll
    for (int i = 0; i < 8; i++) {
      float x = tile[kq + i][nl];
      unsigned short hb = f2bf(x);
      h0[i] = (short)hb;
      l0[i] = (short)f2bf(x - bf2f(hb));
    }
    #pragma unroll
    for (int i = 0; i < 8; i++) {
      float x = tile[kq + 8 + i][nl];
      unsigned short hb = f2bf(x);
      h1[i] = (short)hb;
      l1[i] = (short)f2bf(x - bf2f(hb));
    }
    size_t base = (size_t)n * 256 + k0 + kq;
    *(us8*)&Bh[base] = h0;
    *(us8*)&Bh[base + 8] = h1;
    *(us8*)&Bl[base] = l0;
    *(us8*)&Bl[base + 8] = l1;
  }
}

// --- logits via MFMA: C = (Ah+Al)(Bh+Bl) ~ AhBh + AhBl + AlBh, fp32 accum ---
// 128x128 tile, BK=32, 4 waves (2x2), 4x4 frags of 16x16x32 per wave.
// global_load_lds staging (linear LDS dest + inverse-swizzled global source),
// double-buffered LDS (2-phase), XCD-chunked 1D grid (m-tile innermost),
// swapped mfma operands -> float4 nontemporal stores.
__global__ __launch_bounds__(256, 2) void k_logits_mfma(const float* db3, float* out, const float* ws) {
  __shared__ __align__(16) unsigned short As[2][128 * 64];
  __shared__ __align__(16) unsigned short Bs[2][128 * 64];
  const unsigned short* Ah = (const unsigned short*)(ws + OFF_AH);
  const unsigned short* Al = (const unsigned short*)(ws + OFF_AL);
  const unsigned short* Bh = (const unsigned short*)(ws + OFF_BH);
  const unsigned short* Bl = (const unsigned short*)(ws + OFF_BL);
  int t = threadIdx.x;
  // XCD-chunked mapping: 6256 = 8 XCDs * 782; within an XCD, m-tile cycles
  // fastest so 16 consecutive blocks share one B panel (L2-resident) and the
  // whole A (2 MB) stays in each XCD's L2.
  int bid = blockIdx.x;
  int work = ((bid & 7) * 782) + (bid >> 3);
  int m0 = (work & 15) << 7;     // 16 m-tiles
  int n0 = (work >> 4) << 7;     // 391 n-tiles
  int lane = t & 63;
  int w = t >> 6;
  int wm = w >> 1, wn = w & 1;
  int rr = lane & 15, g = lane >> 4;

  f32x4 acc[4][4];
  #pragma unroll
  for (int i = 0; i < 4; i++)
    #pragma unroll
    for (int j = 0; j < 4; j++)
      acc[i][j] = (f32x4){0.f, 0.f, 0.f, 0.f};

  // STAGE: 4 global_load_lds calls each for As and Bs per K-step.
  // LDS slot s (16B) in [0,1024): row = s>>3, st = s&7.
  // Source slot = st ^ (row&7)  (involution matches the read-side XOR).
  // slot<4 -> hi buffer k-oct slot, else lo buffer k-oct (slot&3).
  auto STAGE = [&](int b, int kk) {
    int k0 = kk * 32;
    #pragma unroll
    for (int p = 0; p < 4; p++) {
      int s = p * 256 + t;             // this lane's LDS slot
      int row = s >> 3;
      int slot = (s & 7) ^ (row & 7);  // inverse-swizzled source slot
      int joct = slot & 3;
      // wave-uniform LDS base: slot p*256 + w*64 (lane offset added by HW)
      unsigned short* ldsA = &As[b][(p * 256 + w * 64) * 8];
      unsigned short* ldsB = &Bs[b][(p * 256 + w * 64) * 8];
      const unsigned short* srcA = ((slot < 4) ? Ah : Al) + (size_t)(m0 + row) * 256 + k0 + joct * 8;
      int nrow = n0 + row;
      if (nrow >= NVOCAB) nrow = NVOCAB - 1;   // clamp: finite garbage, cols never stored
      const unsigned short* srcB = ((slot < 4) ? Bh : Bl) + (size_t)nrow * 256 + k0 + joct * 8;
      GLOAD_LDS16(srcA, ldsA);
      GLOAD_LDS16(srcB, ldsB);
    }
  };

  STAGE(0, 0);
  __syncthreads();   // drains vmcnt(0): tile 0 staged

  #pragma unroll 2
  for (int kk = 0; kk < 8; kk++) {
    if (kk < 7) STAGE((kk + 1) & 1, kk + 1);   // fire-and-forget DMA for next tile
    const unsigned short* Ab = As[kk & 1];
    const unsigned short* Bb = Bs[kk & 1];
    bf16x8 fah[4], fal[4], fbh[4], fbl[4];
    #pragma unroll
    for (int i = 0; i < 4; i++) {
      int m = wm * 64 + i * 16 + rr;
      int base = m * 64, sw = m & 7;
      fah[i] = *(const bf16x8*)&Ab[base + ((g ^ sw) << 3)];
      fal[i] = *(const bf16x8*)&Ab[base + (((4 + g) ^ sw) << 3)];
    }
    #pragma unroll
    for (int j = 0; j < 4; j++) {
      int c = wn * 64 + j * 16 + rr;
      int base = c * 64, sw = c & 7;
      fbh[j] = *(const bf16x8*)&Bb[base + ((g ^ sw) << 3)];
      fbl[j] = *(const bf16x8*)&Bb[base + (((4 + g) ^ sw) << 3)];
    }
    // swapped operands: acc[i][j] holds C[m = ..i..+rr][n = ..j..+g*4+reg]
    #pragma unroll
    for (int i = 0; i < 4; i++)
      #pragma unroll
      for (int j = 0; j < 4; j++) {
        acc[i][j] = __builtin_amdgcn_mfma_f32_16x16x32_bf16(fbh[j], fah[i], acc[i][j], 0, 0, 0);
        acc[i][j] = __builtin_amdgcn_mfma_f32_16x16x32_bf16(fbl[j], fah[i], acc[i][j], 0, 0, 0);
        acc[i][j] = __builtin_amdgcn_mfma_f32_16x16x32_bf16(fbh[j], fal[i], acc[i][j], 0, 0, 0);
      }
    // __syncthreads waits vmcnt(0)+lgkmcnt(0): next tile landed, this tile's reads done
    __syncthreads();
  }

  // epilogue: per (i,j) each lane holds 4 consecutive n for one m -> float4 nt stores
  #pragma unroll
  for (int i = 0; i < 4; i++) {
    int m = m0 + wm * 64 + i * 16 + rr;
    #pragma unroll
    for (int j = 0; j < 4; j++) {
      int nb = n0 + wn * 64 + j * 16 + g * 4;
      if (nb < NVOCAB) {
        f32x4 bias = *(const f32x4*)&db3[nb];
        f32x4 o = acc[i][j] + bias;
        __builtin_nontemporal_store(o, (f32x4*)(out + (size_t)m * NVOCAB + nb));
      }
    }
  }
}

// --- fallback fp32 logits (previous proven kernel) ---
__global__ __launch_bounds__(256) void k_logits(const float* dw3, const float* db3,
                                                float* out, const float* ws) {
  __shared__ __align__(16) float Asl[16 * 128];
  __shared__ __align__(16) float Bsl[16 * 128];
  int t = threadIdx.x;
  int n0 = blockIdx.x * 128;
  int m0 = blockIdx.y * 128;
  int tx = t & 15, ty = t >> 4;
  const float* h2 = ws + OFF_H2;

  float acc[8][8];
  #pragma unroll
  for (int i = 0; i < 8; i++)
    #pragma unroll
    for (int j = 0; j < 8; j++) acc[i][j] = 0.f;

  int ar = t >> 1, ah = t & 1;
  int bk = t >> 4, bn = (t & 15) * 8;
  bool bval = (n0 + bn) < NVOCAB;

  for (int k0 = 0; k0 < 256; k0 += 16) {
    float4 av0 = *(const float4*)&h2[(m0 + ar) * 256 + k0 + ah * 8];
    float4 av1 = *(const float4*)&h2[(m0 + ar) * 256 + k0 + ah * 8 + 4];
    float4 bv0, bv1;
    if (bval) {
      const float* bp = dw3 + (size_t)(k0 + bk) * NVOCAB + n0 + bn;
      bv0 = *(const float4*)bp;
      bv1 = *(const float4*)(bp + 4);
    } else {
      bv0 = make_float4(0.f, 0.f, 0.f, 0.f);
      bv1 = make_float4(0.f, 0.f, 0.f, 0.f);
    }
    __syncthreads();
    {
      int kb = ah * 8;
      Asl[(kb + 0) * 128 + ar] = av0.x;
      Asl[(kb + 1) * 128 + ar] = av0.y;
      Asl[(kb + 2) * 128 + ar] = av0.z;
      Asl[(kb + 3) * 128 + ar] = av0.w;
      Asl[(kb + 4) * 128 + ar] = av1.x;
      Asl[(kb + 5) * 128 + ar] = av1.y;
      Asl[(kb + 6) * 128 + ar] = av1.z;
      Asl[(kb + 7) * 128 + ar] = av1.w;
      *(float4*)&Bsl[bk * 128 + bn] = bv0;
      *(float4*)&Bsl[bk * 128 + bn + 4] = bv1;
    }
    __syncthreads();
    #pragma unroll
    for (int k = 0; k < 16; k++) {
      float4 a0 = *(const float4*)&Asl[k * 128 + ty * 4];
      float4 a1 = *(const float4*)&Asl[k * 128 + 64 + ty * 4];
      float4 b0 = *(const float4*)&Bsl[k * 128 + tx * 4];
      float4 b1 = *(const float4*)&Bsl[k * 128 + 64 + tx * 4];
      float am[8] = {a0.x, a0.y, a0.z, a0.w, a1.x, a1.y, a1.z, a1.w};
      float bm[8] = {b0.x, b0.y, b0.z, b0.w, b1.x, b1.y, b1.z, b1.w};
      #pragma unroll
      for (int i = 0; i < 8; i++)
        #pragma unroll
        for (int j = 0; j < 8; j++)
          acc[i][j] += am[i] * bm[j];
    }
  }
  #pragma unroll
  for (int jj = 0; jj < 2; jj++) {
    int nb = n0 + jj * 64 + tx * 4;
    if (nb < NVOCAB) {
      float4 bias = *(const float4*)&db3[nb];
      #pragma unroll
      for (int i = 0; i < 8; i++) {
        int m = m0 + (i < 4 ? ty * 4 + i : 64 + ty * 4 + (i - 4));
        float4 o;
        o.x = acc[i][jj * 4 + 0] + bias.x;
        o.y = acc[i][jj * 4 + 1] + bias.y;
        o.z = acc[i][jj * 4 + 2] + bias.z;
        o.w = acc[i][jj * 4 + 3] + bias.w;
        *(float4*)&out[(size_t)m * NVOCAB + nb] = o;
      }
    }
  }
}

extern "C" void kernel_launch(void* const* d_in, const int* in_sizes, int n_in,
                              void* d_out, int out_size, void* d_ws, size_t ws_size,
                              hipStream_t stream) {
  const int*   ids = (const int*)d_in[0];
  const float* emb = (const float*)d_in[1];
  const float* dw1 = (const float*)d_in[2];
  const float* db1 = (const float*)d_in[3];
  const float* lng = (const float*)d_in[4];
  const float* lnb = (const float*)d_in[5];
  const float* dw2 = (const float*)d_in[6];
  const float* db2 = (const float*)d_in[7];
  const float* dw3 = (const float*)d_in[8];
  const float* db3 = (const float*)d_in[9];
  const float* cw1 = (const float*)d_in[10];
  const float* cb1 = (const float*)d_in[11];
  const float* cw2 = (const float*)d_in[12];
  const float* cb2 = (const float*)d_in[13];
  const float* cw3 = (const float*)d_in[14];
  const float* cb3 = (const float*)d_in[15];
  const float* sw1 = (const float*)d_in[16];
  const float* sb1 = (const float*)d_in[17];
  const float* sw2 = (const float*)d_in[18];
  const float* sb2 = (const float*)d_in[19];
  float* out = (float*)d_out;
  float* ws  = (float*)d_ws;

  bool mfma_ok = ws_size >= (size_t)WS_TOTAL_F * sizeof(float);

  hipLaunchKernelGGL(k_prep1, dim3(2), dim3(256), 0, stream, ws);
  hipLaunchKernelGGL(k_prep2, dim3(1024), dim3(256), 0, stream, cw1, dw1, ws);
  if (mfma_ok) hipLaunchKernelGGL(k_splitB, dim3(782, 4), dim3(256), 0, stream, dw3, ws);
  hipLaunchKernelGGL(k_spectral, dim3(256), dim3(256), 0, stream, ids, emb, ws);
  hipLaunchKernelGGL(k_concept, dim3(256), dim3(256), 0, stream, cb1, cw2, cb2, cw3, cb3, ws);
  hipLaunchKernelGGL(k_structure, dim3(1), dim3(128), 0, stream, sw1, sb1, sw2, sb2, out, ws);
  hipLaunchKernelGGL(k_decoder, dim3(256), dim3(256), 0, stream, db1, lng, lnb, dw2, db2, ws,
                     mfma_ok ? 1 : 0);
  if (mfma_ok) {
    hipLaunchKernelGGL(k_logits_mfma, dim3(6256), dim3(256), 0, stream, db3, out, ws);
  } else {
    hipLaunchKernelGGL(k_logits, dim3(391, 16), dim3(256), 0, stream, dw3, db3, out, ws);
  }
}